// Round 2
// baseline (85.482 us; speedup 1.0000x reference)
//
#include <hip/hip_runtime.h>

// SE3Transform: out_pos[m*N+n] = R[batch[n]+16m] @ xyz[n] + p[batch[n]+16m]
//               out_batch[m*N+n] = batch[n] + 16m (as float)
// N=500000, B=16, M=8. Kernel floor: 64MB W + ~10MB R => ~12us @6.3TB/s.
// (Timed graph also contains the harness 268MB poison fill, ~44.5us fixed.)
//
// R3 kernel measured ~38.6us (just below the 44us fills in rocprof rank).
// R4 theory: latency/overhead-bound, not BW-bound. Strip the wave critical
// path: drop the s_x LDS window (2 aligned global dwordx4 + cndmask select
// instead), let pure-batch blocks skip staging+barrier, nontemporal stores
// so the 64MB write stream doesn't thrash L2 for the cached reads.
// R5: __builtin_nontemporal_store needs a native clang vector type, not
// HIP's float4 class -> store through ext_vector_type(4) float.

#define NPTS   500000
#define POSF4  375000     // pos float4s per m-slice
#define BATF4  125000     // batch float4s per m-slice
#define NT     128
#define TSTR   20         // dword stride per matrix in LDS (bank spread)

typedef float f32x4 __attribute__((ext_vector_type(4)));

__device__ __forceinline__ void nt_store4(float4 v, float4* p) {
    f32x4 w; w.x = v.x; w.y = v.y; w.z = v.z; w.w = v.w;
    __builtin_nontemporal_store(w, (f32x4*)p);
}

__global__ __launch_bounds__(256) void se3_kernel(
    const float* __restrict__ trans,   // [128,4,4]
    const float* __restrict__ xyz,     // [N,3]
    const int*   __restrict__ batch,   // [N]
    float* __restrict__ out)           // [12M pos floats][4M batch floats]
{
    __shared__ float s_t[NT * TSTR];   // 10,240 B

    const int tid = threadIdx.x;
    const int F   = blockIdx.x * 256;
    const int t   = F + tid;

    // Pure-batch blocks (F >= POSF4) never read s_t: skip stage + barrier.
    if (F < POSF4) {
        // Stage trans -> LDS (512 f4, 2/thread). Row c of matrix nb at dword
        // nb*20 + c*4 = [Rc0 Rc1 Rc2 pc].
        for (int i = tid; i < NT * 4; i += 256) {
            int pt = i >> 2, row = i & 3;
            float4 v = ((const float4*)trans)[i];
            *(float4*)&s_t[pt * TSTR + row * 4] = v;
        }
        __syncthreads();
    }

    if (t < POSF4) {
        const int f  = t;
        const int t3 = f % 3;
        const int w  = 4 * f - t3;       // = 3*n0: first xyz dword this f4 needs
        const int n0 = w / 3;            // first point (exact: 3 | w)

        // Need xyz dwords [w, w+5] = x,y,z of points n0, n0+1.
        // Two ALIGNED float4 loads cover dwords [a0, a0+8); all lanes in
        // bounds (max a0+7 = 1,499,995 for t3==0; a0 >= 0 for f >= 1).
        // t3==1 (shift 3) additionally needs dword a0+8 = w+5 <= 1,499,999.
        const int a0 = w & ~3;
        const float4 v0 = *(const float4*)(xyz + a0);
        const float4 v1 = *(const float4*)(xyz + a0 + 4);
        const float  d8 = xyz[t3 == 1 ? a0 + 8 : a0];

        // Select the 6 window floats at shift s = w&3 (t3=0->0, 1->3, 2->2).
        const float xa = t3 == 0 ? v0.x : (t3 == 1 ? v0.w : v0.z);
        const float xb = t3 == 0 ? v0.y : (t3 == 1 ? v1.x : v0.w);
        const float xc = t3 == 0 ? v0.z : (t3 == 1 ? v1.y : v1.x);
        const float xd = t3 == 0 ? v0.w : (t3 == 1 ? v1.z : v1.y);
        const float xe = t3 == 0 ? v1.x : (t3 == 1 ? v1.w : v1.z);
        const float xf = t3 == 0 ? v1.y : (t3 == 1 ? d8   : v1.w);

        const int b0 = batch[n0];
        const int b1 = batch[n0 + 1];

        // Per output comp k: c_k=(t3+k)%3, sel_k=(t3+k)/3; m-invariant
        // byte offset into s_t, and the point's xyz comps.
        int   ro[4];
        float X0[4], X1[4], X2[4];
        #pragma unroll
        for (int k = 0; k < 4; ++k) {
            int ck = t3 + k, sel = 0;
            if (ck >= 3) { ck -= 3; sel = 1; }
            int b = sel ? b1 : b0;
            ro[k] = b * (TSTR * 4) + ck * 16;    // bytes
            X0[k] = sel ? xd : xa;
            X1[k] = sel ? xe : xb;
            X2[k] = sel ? xf : xc;
        }

        const char* stb = (const char*)s_t;
        float4* po = (float4*)out;
        #pragma unroll
        for (int m = 0; m < 8; ++m) {
            // m stride = 16 matrices * 20 dwords * 4B = 1280B (imm offset)
            float4 r0 = *(const float4*)(stb + ro[0] + m * 1280);
            float4 r1 = *(const float4*)(stb + ro[1] + m * 1280);
            float4 r2 = *(const float4*)(stb + ro[2] + m * 1280);
            float4 r3 = *(const float4*)(stb + ro[3] + m * 1280);
            float4 v;
            v.x = fmaf(r0.x, X0[0], fmaf(r0.y, X1[0], fmaf(r0.z, X2[0], r0.w)));
            v.y = fmaf(r1.x, X0[1], fmaf(r1.y, X1[1], fmaf(r1.z, X2[1], r1.w)));
            v.z = fmaf(r2.x, X0[2], fmaf(r2.y, X1[2], fmaf(r2.z, X2[2], r2.w)));
            v.w = fmaf(r3.x, X0[3], fmaf(r3.y, X1[3], fmaf(r3.z, X2[3], r3.w)));
            nt_store4(v, &po[m * POSF4 + f]);    // lane-contiguous, coalesced
        }
    } else if (t < POSF4 + BATF4) {
        const int q = t - POSF4;
        int4 b4 = ((const int4*)batch)[q];
        float4* ob = (float4*)(out + 12000000);
        #pragma unroll
        for (int m = 0; m < 8; ++m) {
            const int a = m * 16;
            float4 v = make_float4((float)(b4.x + a), (float)(b4.y + a),
                                   (float)(b4.z + a), (float)(b4.w + a));
            nt_store4(v, &ob[m * BATF4 + q]);
        }
    }
}

extern "C" void kernel_launch(void* const* d_in, const int* in_sizes, int n_in,
                              void* d_out, int out_size, void* d_ws, size_t ws_size,
                              hipStream_t stream) {
    const float* trans = (const float*)d_in[0];   // 2048 floats
    const float* xyz   = (const float*)d_in[1];   // 1,500,000 floats
    const int*   batch = (const int*)d_in[2];     // 500,000 ints
    float* out = (float*)d_out;                   // 16,000,000 floats

    const int total = POSF4 + BATF4;              // 500,000 work items
    const int block = 256;
    const int grid  = (total + block - 1) / block; // 1954
    se3_kernel<<<grid, block, 0, stream>>>(trans, xyz, batch, out);
}

// Round 3
// 84.334 us; speedup vs baseline: 1.0136x; 1.0136x over previous
//
#include <hip/hip_runtime.h>

// SE3Transform: out_pos[m*N+n] = R[batch[n]+16m] @ xyz[n] + p[batch[n]+16m]
//               out_batch[m*N+n] = batch[n] + 16m (as float)
// N=500000, B=16, M=8. Kernel floor: 64MB W + ~10MB R => ~12us @6.3TB/s.
// (Timed graph also contains harness poison fills, ~44.5us+ fixed.)
//
// R6: revert nontemporal stores (R2: +2.4us regression). Latency theory:
// the whole grid is one resident generation, so kernel time ~= one wave's
// serial critical path. (a) issue per-thread xyz/batch loads BEFORE the
// trans staging + barrier so their latency hides under staging; (b) split
// the m-loop across 2 blocks (mh = blockIdx.x & 1, m in [4mh, 4mh+4)):
// halves each wave's dependent chain, doubles TLP, halves LDS (stage only
// the 64 matrices this half uses).

#define NPTS   500000
#define POSF4  375000     // pos float4s per m-slice
#define BATF4  125000     // batch float4s per m-slice
#define TSTR   20         // dword stride per matrix in LDS (bank spread)

__global__ __launch_bounds__(256) void se3_kernel(
    const float* __restrict__ trans,   // [128,4,4]
    const float* __restrict__ xyz,     // [N,3]
    const int*   __restrict__ batch,   // [N]
    float* __restrict__ out)           // [12M pos floats][4M batch floats]
{
    __shared__ float s_t[64 * TSTR];   // 5,120 B: the 64 matrices for this mh

    const int tid   = threadIdx.x;
    const int bx    = blockIdx.x;
    const int chunk = bx >> 1;
    const int mh    = bx & 1;          // this block handles m in [4mh, 4mh+4)
    const int F     = chunk * 256;
    const int t     = F + tid;

    const bool isPos = t < POSF4;

    // --- early per-thread global loads: latency overlaps staging+barrier ---
    float4 v0, v1; float d8 = 0.f; int b0 = 0, b1 = 0, t3 = 0;
    v0 = make_float4(0.f, 0.f, 0.f, 0.f); v1 = v0;
    if (isPos) {
        const int f  = t;
        t3 = f % 3;
        const int w  = 4 * f - t3;     // = 3*n0: first xyz dword this f4 needs
        const int n0 = w / 3;          // first point (exact: 3 | w)
        // Two ALIGNED float4 loads cover dwords [a0, a0+8); all in bounds.
        // t3==1 additionally needs dword a0+8 = w+5 <= 1,499,999.
        const int a0 = w & ~3;
        v0 = *(const float4*)(xyz + a0);
        v1 = *(const float4*)(xyz + a0 + 4);
        d8 = xyz[t3 == 1 ? a0 + 8 : a0];
        b0 = batch[n0];
        b1 = batch[n0 + 1];
    }

    // Pure-batch blocks (F >= POSF4) never read s_t: skip stage + barrier.
    if (F < POSF4) {
        // Stage this half's 64 matrices (256 f4, exactly 1 per thread).
        // Row c of matrix nb at dword nb*20 + c*4 = [Rc0 Rc1 Rc2 pc].
        {
            const int i = tid;                 // 0..255
            const int pt = i >> 2, row = i & 3;
            float4 v = ((const float4*)trans)[256 * mh + i];
            *(float4*)&s_t[pt * TSTR + row * 4] = v;
        }
        __syncthreads();
    }

    if (isPos) {
        const int f = t;
        // Select the 6 window floats at shift (t3=0->0, 1->3, 2->2).
        const float xa = t3 == 0 ? v0.x : (t3 == 1 ? v0.w : v0.z);
        const float xb = t3 == 0 ? v0.y : (t3 == 1 ? v1.x : v0.w);
        const float xc = t3 == 0 ? v0.z : (t3 == 1 ? v1.y : v1.x);
        const float xd = t3 == 0 ? v0.w : (t3 == 1 ? v1.z : v1.y);
        const float xe = t3 == 0 ? v1.x : (t3 == 1 ? v1.w : v1.z);
        const float xf = t3 == 0 ? v1.y : (t3 == 1 ? d8   : v1.w);

        // Per output comp k: c_k=(t3+k)%3, sel_k=(t3+k)/3; m-invariant
        // byte offset into s_t, and the point's xyz comps.
        int   ro[4];
        float X0[4], X1[4], X2[4];
        #pragma unroll
        for (int k = 0; k < 4; ++k) {
            int ck = t3 + k, sel = 0;
            if (ck >= 3) { ck -= 3; sel = 1; }
            int b = sel ? b1 : b0;
            ro[k] = b * (TSTR * 4) + ck * 16;    // bytes
            X0[k] = sel ? xd : xa;
            X1[k] = sel ? xe : xb;
            X2[k] = sel ? xf : xc;
        }

        const char* stb = (const char*)s_t;
        float4* po = (float4*)out;
        #pragma unroll
        for (int mm = 0; mm < 4; ++mm) {
            const int m = 4 * mh + mm;
            // mm stride = 16 matrices * 20 dwords * 4B = 1280B (imm offset)
            float4 r0 = *(const float4*)(stb + ro[0] + mm * 1280);
            float4 r1 = *(const float4*)(stb + ro[1] + mm * 1280);
            float4 r2 = *(const float4*)(stb + ro[2] + mm * 1280);
            float4 r3 = *(const float4*)(stb + ro[3] + mm * 1280);
            float4 v;
            v.x = fmaf(r0.x, X0[0], fmaf(r0.y, X1[0], fmaf(r0.z, X2[0], r0.w)));
            v.y = fmaf(r1.x, X0[1], fmaf(r1.y, X1[1], fmaf(r1.z, X2[1], r1.w)));
            v.z = fmaf(r2.x, X0[2], fmaf(r2.y, X1[2], fmaf(r2.z, X2[2], r2.w)));
            v.w = fmaf(r3.x, X0[3], fmaf(r3.y, X1[3], fmaf(r3.z, X2[3], r3.w)));
            po[m * POSF4 + f] = v;               // lane-contiguous, coalesced
        }
    } else if (t < POSF4 + BATF4) {
        const int q = t - POSF4;
        int4 b4 = ((const int4*)batch)[q];
        float4* ob = (float4*)(out + 12000000);
        #pragma unroll
        for (int mm = 0; mm < 4; ++mm) {
            const int m = 4 * mh + mm;
            const int a = m * 16;
            ob[m * BATF4 + q] = make_float4((float)(b4.x + a), (float)(b4.y + a),
                                            (float)(b4.z + a), (float)(b4.w + a));
        }
    }
}

extern "C" void kernel_launch(void* const* d_in, const int* in_sizes, int n_in,
                              void* d_out, int out_size, void* d_ws, size_t ws_size,
                              hipStream_t stream) {
    const float* trans = (const float*)d_in[0];   // 2048 floats
    const float* xyz   = (const float*)d_in[1];   // 1,500,000 floats
    const int*   batch = (const int*)d_in[2];     // 500,000 ints
    float* out = (float*)d_out;                   // 16,000,000 floats

    const int total = POSF4 + BATF4;              // 500,000 work items
    const int block = 256;
    const int chunks = (total + block - 1) / block;   // 1954
    const int grid   = 2 * chunks;                    // 3908 (m split in half)
    se3_kernel<<<grid, block, 0, stream>>>(trans, xyz, batch, out);
}

// Round 4
// 82.023 us; speedup vs baseline: 1.0422x; 1.0282x over previous
//
#include <hip/hip_runtime.h>

// SE3Transform: out_pos[m*N+n] = R[batch[n]+16m] @ xyz[n] + p[batch[n]+16m]
//               out_batch[m*N+n] = batch[n] + 16m (as float)
// N=500000, B=16, M=8.
//
// R7 CONCLUSION: timed graph = 256MiB poison fill (44.5us, harness-fixed)
// + 4 kernel launches (~9.7us each = 64MB writes @ ~6.6TB/s, at the
// achievable write-BW ceiling; fill itself sustains 6.0TB/s). Evidence:
// fill WRITE_SIZE = 4x output image; 44.5 + 4*9.7 = 83.3 ~= 83.1 measured;
// three structural attacks (drop s_x staging R4/5, m-split + early loads +
// 2x TLP R6) all null within +-2%; nontemporal stores REGRESS +2.4us
// (writes benefit from L3 absorption). Kernel is write-BW-bound at floor.
// This is the best-measured variant (R0, 83.1us) reverted verbatim.

#define NPTS   500000
#define POSF4  375000     // pos float4s per m-slice
#define BATF4  125000     // batch float4s per m-slice
#define NT     128
#define TSTR   20         // dword stride per matrix in LDS (bank spread)

__global__ __launch_bounds__(256) void se3_kernel(
    const float* __restrict__ trans,   // [128,4,4]
    const float* __restrict__ xyz,     // [N,3]
    const int*   __restrict__ batch,   // [N]
    float* __restrict__ out)           // [12M pos floats][4M batch floats]
{
    __shared__ float  s_t[NT * TSTR];  // 10,240 B
    __shared__ float4 s_x[264];        //  4,224 B: xyz f4 window [F-2, F+262)

    const int tid = threadIdx.x;
    const int F   = blockIdx.x * 256;
    const int t   = F + tid;

    // Stage trans -> LDS (512 f4, 2/thread). Row c of matrix nb at dword
    // nb*20 + c*4 = [Rc0 Rc1 Rc2 pc].
    for (int i = tid; i < NT * 4; i += 256) {
        int pt = i >> 2, row = i & 3;
        float4 v = ((const float4*)trans)[i];
        *(float4*)&s_t[pt * TSTR + row * 4] = v;
    }
    // Stage xyz window for pos blocks (coalesced f4 loads, clamped).
    if (F < POSF4) {
        for (int i = tid; i < 264; i += 256) {
            int idx = F - 2 + i;
            idx = idx < 0 ? 0 : (idx >= POSF4 ? POSF4 - 1 : idx);
            s_x[i] = ((const float4*)xyz)[idx];
        }
    }
    __syncthreads();

    if (t < POSF4) {
        const int f  = t;
        const int t3 = f % 3;
        const int n0 = (4 * f - t3) / 3;         // first point this f4 touches

        // 6 xyz floats [4f-t3 .. 4f-t3+5] from the window.
        const float* sxf = (const float*)s_x;
        const int off = 4 * tid + 8 - t3;
        float xa = sxf[off + 0], xb = sxf[off + 1], xc = sxf[off + 2];
        float xd = sxf[off + 3], xe = sxf[off + 4], xf = sxf[off + 5];

        const int b0 = batch[n0];
        const int b1 = batch[n0 + 1];

        // Per output comp k: c_k=(t3+k)%3, sel_k=(t3+k)/3; m-invariant
        // byte offset into s_t, and the point's xyz comps.
        int   ro[4];
        float X0[4], X1[4], X2[4];
        #pragma unroll
        for (int k = 0; k < 4; ++k) {
            int ck = t3 + k, sel = 0;
            if (ck >= 3) { ck -= 3; sel = 1; }
            int b = sel ? b1 : b0;
            ro[k] = b * (TSTR * 4) + ck * 16;    // bytes
            X0[k] = sel ? xd : xa;
            X1[k] = sel ? xe : xb;
            X2[k] = sel ? xf : xc;
        }

        const char* stb = (const char*)s_t;
        float4* po = (float4*)out;
        #pragma unroll
        for (int m = 0; m < 8; ++m) {
            // m stride = 16 matrices * 20 dwords * 4B = 1280B (imm offset)
            float4 r0 = *(const float4*)(stb + ro[0] + m * 1280);
            float4 r1 = *(const float4*)(stb + ro[1] + m * 1280);
            float4 r2 = *(const float4*)(stb + ro[2] + m * 1280);
            float4 r3 = *(const float4*)(stb + ro[3] + m * 1280);
            float4 v;
            v.x = fmaf(r0.x, X0[0], fmaf(r0.y, X1[0], fmaf(r0.z, X2[0], r0.w)));
            v.y = fmaf(r1.x, X0[1], fmaf(r1.y, X1[1], fmaf(r1.z, X2[1], r1.w)));
            v.z = fmaf(r2.x, X0[2], fmaf(r2.y, X1[2], fmaf(r2.z, X2[2], r2.w)));
            v.w = fmaf(r3.x, X0[3], fmaf(r3.y, X1[3], fmaf(r3.z, X2[3], r3.w)));
            po[m * POSF4 + f] = v;               // lane-contiguous, coalesced
        }
    } else if (t < POSF4 + BATF4) {
        const int q = t - POSF4;
        int4 b4 = ((const int4*)batch)[q];
        float4* ob = (float4*)(out + 12000000);
        #pragma unroll
        for (int m = 0; m < 8; ++m) {
            const int a = m * 16;
            ob[m * BATF4 + q] = make_float4((float)(b4.x + a), (float)(b4.y + a),
                                            (float)(b4.z + a), (float)(b4.w + a));
        }
    }
}

extern "C" void kernel_launch(void* const* d_in, const int* in_sizes, int n_in,
                              void* d_out, int out_size, void* d_ws, size_t ws_size,
                              hipStream_t stream) {
    const float* trans = (const float*)d_in[0];   // 2048 floats
    const float* xyz   = (const float*)d_in[1];   // 1,500,000 floats
    const int*   batch = (const int*)d_in[2];     // 500,000 ints
    float* out = (float*)d_out;                   // 16,000,000 floats

    const int total = POSF4 + BATF4;              // 500,000 work items
    const int block = 256;
    const int grid  = (total + block - 1) / block; // 1954
    se3_kernel<<<grid, block, 0, stream>>>(trans, xyz, batch, out);
}